// Round 2
// baseline (943.374 us; speedup 1.0000x reference)
//
#include <hip/hip_runtime.h>
#include <stdint.h>

#define B_ 64
#define T_ 4096
#define C_ 64
#define COND_ 512
#define H_ 256

typedef __attribute__((ext_vector_type(8))) short short8;
typedef __attribute__((ext_vector_type(4))) float f32x4;
typedef __attribute__((ext_vector_type(2))) float f32x2;
typedef __attribute__((ext_vector_type(2))) unsigned int u32x2;

__device__ __forceinline__ unsigned short f2bf(float x) {
  union { float f; unsigned u; } v; v.f = x;
  unsigned r = v.u + 0x7FFFu + ((v.u >> 16) & 1u);
  return (unsigned short)(r >> 16);
}

// ws layout (bytes)
#define WS_W1   0          // 17*16*64*8 bf16 = 278528 B (A-frag layout, GEMM1)
#define WS_W2   278528     // 8*4*64*8  bf16 = 32768 B  (A-frag layout, GEMM2, *exp(3*logs2))
#define WS_PB   311296     // 64 f32: actnorm_bias[perm[c]]
#define WS_PS   311552     // 64 f32: exp(actnorm_logs[perm[c]])
#define WS_B2S  311808     // 64 f32: b2*exp(3*logs2)

// ---------------------------------------------------------------------------
// Prep: weight repack to bf16 fragment layout + folded per-channel tables +
// logdet init. Runs every launch (graph-capture safe), ~1 MB of L2 traffic.
// ---------------------------------------------------------------------------
__global__ __launch_bounds__(256) void prep_kernel(
    const float* __restrict__ W1, const float* __restrict__ W2,
    const float* __restrict__ anb, const float* __restrict__ anl,
    const int* __restrict__ perm, const float* __restrict__ b2,
    const float* __restrict__ logs2,
    unsigned short* __restrict__ wsW1, unsigned short* __restrict__ wsW2,
    float* __restrict__ pb, float* __restrict__ ps, float* __restrict__ b2s,
    float* __restrict__ out_ld)
{
  int id = blockIdx.x * 256 + threadIdx.x;
  if (id < 544 * 256) {
    // W1T[f][k] = W1[k<512 ? k+32 : k-512][f]  (cond rows first, z1 rows last)
    int feat = id & 255, k = id >> 8;
    int r = (k < 512) ? (k + 32) : (k - 512);
    float v = W1[r * 256 + feat];
    int s = k >> 5, MI = feat >> 4;
    int l = (feat & 15) + 16 * ((k >> 3) & 3), i = k & 7;
    wsW1[((s * 16 + MI) * 64 + l) * 8 + i] = f2bf(v);
  } else if (id < 544 * 256 + 256 * 64) {
    int id2 = id - 544 * 256;
    int ch = id2 & 63, k = id2 >> 6;
    float v = W2[k * 64 + ch] * expf(logs2[ch] * 3.0f);
    int s2 = k >> 5, MI2 = ch >> 4;
    int l = (ch & 15) + 16 * ((k >> 3) & 3), i = k & 7;
    wsW2[((s2 * 4 + MI2) * 64 + l) * 8 + i] = f2bf(v);
  } else {
    int c = id - (544 * 256 + 256 * 64);
    if (c < 64) {
      int p = perm[c];
      pb[c] = anb[p];
      ps[c] = expf(anl[p]);
    } else if (c < 128) {
      int ch = c - 64;
      b2s[ch] = b2[ch] * expf(logs2[ch] * 3.0f);
    } else if (c < 192) {
      int b = c - 128;
      float s = 0.f;
      for (int j = 0; j < 64; ++j) s += anl[j];
      out_ld[b] = (float)T_ * s;   // logdet init, atomics add the rest
    }
  }
}

// ---------------------------------------------------------------------------
// Main fused kernel. 64 tokens/block, 256 threads (4 waves).
// GEMM1 (swapped): H^T(256x64) = W1T(256x544) @ A^T(544x64), K double-buffered.
// GEMM2 (swapped): OUT^T(64x64) = W2T(64x256) @ H^T(256x64).
// lA (GEMM1 staging, 16 KB) and lHT (GEMM2 input, 32 KB) have disjoint
// lifetimes separated by a barrier -> UNION alias. LDS 48->32 KB gives
// 5 blocks/CU (20 waves/CU) instead of 3 for latency hiding.
// Epilogue: actnorm+perm gathers, sigmoid/shift/scale, logdet reduce.
// ---------------------------------------------------------------------------
__global__ __launch_bounds__(256, 5) void flow_main(
    const float* __restrict__ input, const float* __restrict__ cond,
    const int* __restrict__ perm, const float* __restrict__ b1,
    const unsigned short* __restrict__ wsW1, const unsigned short* __restrict__ wsW2,
    const float* __restrict__ pb, const float* __restrict__ ps,
    const float* __restrict__ b2s,
    float* __restrict__ out, float* __restrict__ out_ld)
{
  __shared__ union SM {
    short lA[2][64 * 64];   // [buf][tok][k] bf16, 16B-slot XOR swizzle (GEMM1)
    short lHT[64 * 256];    // [tok][feat] bf16, XOR swizzle (GEMM2)
  } sm;

  const int tid = threadIdx.x;
  const int w  = tid >> 6;
  const int l  = tid & 63;
  const int lr = l & 15;
  const int lh = l >> 4;
  const long long m0 = (long long)blockIdx.x * 64;

  // ---- stage K-tile 0 = z1 (32 permuted+actnormed input channels) into lA[0]
  {
    const int tok = tid >> 2;
    const int c0 = (tid & 3) * 8;
    const float* ip = input + (m0 + tok) * 64;
    short8 v;
#pragma unroll
    for (int j = 0; j < 8; ++j) {
      int c = c0 + j;
      v[j] = (short)f2bf((ip[perm[c]] + pb[c]) * ps[c]);
    }
    const int S = (tid & 3) ^ (tok & 7);
    *(short8*)&sm.lA[0][tok * 64 + S * 8] = v;
  }
  __syncthreads();

  f32x4 acc[4][4];
#pragma unroll
  for (int mi = 0; mi < 4; ++mi)
#pragma unroll
    for (int nj = 0; nj < 4; ++nj)
      acc[mi][nj] = (f32x4)0.0f;

  const int stok = tid >> 2;
  const int skc = (tid & 3) * 16;

  // it=0 consumes z1 tile (1 K-step, s=16); it=1..8 consume cond tiles (2 K-steps)
#pragma unroll 1
  for (int it = 0; it <= 8; ++it) {
    const int buf = it & 1;

    // issue next cond stage loads (k0 = it*64) early — latency hides under MFMA
    f32x4 st0, st1, st2, st3;
    if (it < 8) {
      const float* cp = cond + (m0 + stok) * 512 + (it * 64 + skc);
      st0 = *(const f32x4*)(cp);
      st1 = *(const f32x4*)(cp + 4);
      st2 = *(const f32x4*)(cp + 8);
      st3 = *(const f32x4*)(cp + 12);
    }

    const int nk = (it == 0) ? 1 : 2;
    const int sbase = (it == 0) ? 16 : 2 * (it - 1);

    short8 af[2][4], bf[2][4];
#pragma unroll
    for (int h = 0; h < 2; ++h) {
      if (h < nk) {
#pragma unroll
        for (int mi = 0; mi < 4; ++mi)
          af[h][mi] = *(const short8*)&wsW1[(((sbase + h) * 16 + (4 * w + mi)) * 64 + l) * 8];
#pragma unroll
        for (int nj = 0; nj < 4; ++nj) {
          int tok = 16 * nj + lr;
          int S = (4 * h + lh) ^ (tok & 7);
          bf[h][nj] = *(const short8*)&sm.lA[buf][tok * 64 + S * 8];
        }
      }
    }

#pragma unroll
    for (int h = 0; h < 2; ++h) {
      if (h < nk) {
#pragma unroll
        for (int mi = 0; mi < 4; ++mi)
#pragma unroll
          for (int nj = 0; nj < 4; ++nj)
            acc[mi][nj] = __builtin_amdgcn_mfma_f32_16x16x32_bf16(
                af[h][mi], bf[h][nj], acc[mi][nj], 0, 0, 0);
      }
    }

    // convert staged f32 -> bf16, write next buffer
    if (it < 8) {
      short8 c0v, c1v;
      c0v[0] = (short)f2bf(st0[0]); c0v[1] = (short)f2bf(st0[1]);
      c0v[2] = (short)f2bf(st0[2]); c0v[3] = (short)f2bf(st0[3]);
      c0v[4] = (short)f2bf(st1[0]); c0v[5] = (short)f2bf(st1[1]);
      c0v[6] = (short)f2bf(st1[2]); c0v[7] = (short)f2bf(st1[3]);
      c1v[0] = (short)f2bf(st2[0]); c1v[1] = (short)f2bf(st2[1]);
      c1v[2] = (short)f2bf(st2[2]); c1v[3] = (short)f2bf(st2[3]);
      c1v[4] = (short)f2bf(st3[0]); c1v[5] = (short)f2bf(st3[1]);
      c1v[6] = (short)f2bf(st3[2]); c1v[7] = (short)f2bf(st3[3]);
      const int S0 = 2 * (tid & 3);
      *(short8*)&sm.lA[buf ^ 1][stok * 64 + ((S0 ^ (stok & 7)) * 8)] = c0v;
      *(short8*)&sm.lA[buf ^ 1][stok * 64 + (((S0 + 1) ^ (stok & 7)) * 8)] = c1v;
    }
    __syncthreads();
  }

  // ---- h = leaky_relu(acc + b1) -> lHT[tok][feat] bf16 (packed b64 writes)
  // lA is dead from here (barrier above) — lHT aliases it.
#pragma unroll
  for (int mi = 0; mi < 4; ++mi) {
    const int f0 = 64 * w + 16 * mi + 4 * lh;
    const f32x4 b1v = *(const f32x4*)&b1[f0];
#pragma unroll
    for (int nj = 0; nj < 4; ++nj) {
      const int tok = 16 * nj + lr;
      f32x4 v = acc[mi][nj];
      float h0 = v[0] + b1v[0]; h0 = h0 > 0.f ? h0 : 0.01f * h0;
      float h1 = v[1] + b1v[1]; h1 = h1 > 0.f ? h1 : 0.01f * h1;
      float h2 = v[2] + b1v[2]; h2 = h2 > 0.f ? h2 : 0.01f * h2;
      float h3 = v[3] + b1v[3]; h3 = h3 > 0.f ? h3 : 0.01f * h3;
      u32x2 p;
      p[0] = (unsigned)f2bf(h0) | ((unsigned)f2bf(h1) << 16);
      p[1] = (unsigned)f2bf(h2) | ((unsigned)f2bf(h3) << 16);
      const int off = (tok * 512 + f0 * 2) ^ ((tok & 7) << 4);
      *(u32x2*)((char*)sm.lHT + off) = p;
    }
  }

  // prefetch GEMM2 A-frags (L2-hot) — latency hides in the barrier wait
  short8 a2r[8];
#pragma unroll
  for (int s2 = 0; s2 < 8; ++s2)
    a2r[s2] = *(const short8*)&wsW2[((s2 * 4 + w) * 64 + l) * 8];

  __syncthreads();

  // ---- GEMM2: OUT^T = W2T @ H^T
  f32x4 acc2[4];
#pragma unroll
  for (int nj = 0; nj < 4; ++nj) acc2[nj] = (f32x4)0.0f;

#pragma unroll
  for (int s2 = 0; s2 < 8; ++s2) {
#pragma unroll
    for (int nj = 0; nj < 4; ++nj) {
      const int tok = 16 * nj + lr;
      const int off = (tok * 512 + (32 * s2 + 8 * lh) * 2) ^ ((tok & 7) << 4);
      const short8 hb = *(const short8*)((char*)sm.lHT + off);
      acc2[nj] = __builtin_amdgcn_mfma_f32_16x16x32_bf16(a2r[s2], hb, acc2[nj], 0, 0, 0);
    }
  }

  // ---- epilogue: lane holds out-channels {2j0, 2j0+1, 2j0+2, 2j0+3}
  const int j0 = 8 * w + 2 * lh;              // z2-pair indices j0, j0+1
  const int pA = perm[j0],      pB = perm[j0 + 1];
  const int pC = perm[32 + j0], pD = perm[33 + j0];
  const float bA = pb[j0],      sA = ps[j0];
  const float bB = pb[j0 + 1],  sB = ps[j0 + 1];
  const float bC = pb[32 + j0], sC = ps[32 + j0];
  const float bD = pb[33 + j0], sD = ps[33 + j0];
  const f32x4 b2v = *(const f32x4*)&b2s[16 * w + 4 * lh];

  float ldp = 0.f;
#pragma unroll
  for (int nj = 0; nj < 4; ++nj) {
    const long long row = m0 + 16 * nj + lr;
    const float* ip = input + row * 64;
    float* op = out + row * 64;
    f32x4 v = acc2[nj];
    const float sh0 = v[0] + b2v[0];
    const float sc0 = v[1] + b2v[1];
    const float sh1 = v[2] + b2v[2];
    const float sc1 = v[3] + b2v[3];
    const float scl0 = fmaxf(1.f / (1.f + expf(-(sc0 + 2.f))), 1e-6f);
    const float scl1 = fmaxf(1.f / (1.f + expf(-(sc1 + 2.f))), 1e-6f);
    f32x2 z1o, z2o;
    z1o[0] = (ip[pA] + bA) * sA;
    z1o[1] = (ip[pB] + bB) * sB;
    z2o[0] = ((ip[pC] + bC) * sC + sh0) * scl0;
    z2o[1] = ((ip[pD] + bD) * sD + sh1) * scl1;
    *(f32x2*)(op + j0) = z1o;
    *(f32x2*)(op + 32 + j0) = z2o;
    ldp += logf(scl0) + logf(scl1);
  }

#pragma unroll
  for (int off = 32; off > 0; off >>= 1) ldp += __shfl_xor(ldp, off, 64);
  if (l == 0) atomicAdd(&out_ld[blockIdx.x >> 6], ldp);
}

extern "C" void kernel_launch(void* const* d_in, const int* in_sizes, int n_in,
                              void* d_out, int out_size, void* d_ws, size_t ws_size,
                              hipStream_t stream)
{
  const float* input = (const float*)d_in[0];
  const float* cond  = (const float*)d_in[1];
  const float* anb   = (const float*)d_in[2];
  const float* anl   = (const float*)d_in[3];
  const int*   perm  = (const int*)d_in[4];
  const float* W1    = (const float*)d_in[5];
  const float* b1    = (const float*)d_in[6];
  const float* W2    = (const float*)d_in[7];
  const float* b2    = (const float*)d_in[8];
  const float* logs2 = (const float*)d_in[9];

  float* out    = (float*)d_out;
  float* out_ld = out + (long long)B_ * T_ * C_;

  char* ws = (char*)d_ws;
  unsigned short* wsW1 = (unsigned short*)(ws + WS_W1);
  unsigned short* wsW2 = (unsigned short*)(ws + WS_W2);
  float* pbp  = (float*)(ws + WS_PB);
  float* psp  = (float*)(ws + WS_PS);
  float* b2sp = (float*)(ws + WS_B2S);

  prep_kernel<<<609, 256, 0, stream>>>(W1, W2, anb, anl, perm, b2, logs2,
                                       wsW1, wsW2, pbp, psp, b2sp, out_ld);
  flow_main<<<4096, 256, 0, stream>>>(input, cond, perm, b1, wsW1, wsW2,
                                      pbp, psp, b2sp, out, out_ld);
}

// Round 3
// 331.263 us; speedup vs baseline: 2.8478x; 2.8478x over previous
//
#include <hip/hip_runtime.h>
#include <stdint.h>

#define B_ 64
#define T_ 4096
#define C_ 64
#define COND_ 512
#define H_ 256

typedef __attribute__((ext_vector_type(8))) short short8;
typedef __attribute__((ext_vector_type(4))) float f32x4;
typedef __attribute__((ext_vector_type(2))) float f32x2;
typedef __attribute__((ext_vector_type(2))) unsigned int u32x2;

__device__ __forceinline__ unsigned short f2bf(float x) {
  union { float f; unsigned u; } v; v.f = x;
  unsigned r = v.u + 0x7FFFu + ((v.u >> 16) & 1u);
  return (unsigned short)(r >> 16);
}

__device__ __forceinline__ short8 cvt8(f32x4 lo, f32x4 hi) {
  short8 t;
  t[0] = (short)f2bf(lo[0]); t[1] = (short)f2bf(lo[1]);
  t[2] = (short)f2bf(lo[2]); t[3] = (short)f2bf(lo[3]);
  t[4] = (short)f2bf(hi[0]); t[5] = (short)f2bf(hi[1]);
  t[6] = (short)f2bf(hi[2]); t[7] = (short)f2bf(hi[3]);
  return t;
}

// ws layout (bytes)
#define WS_W1   0          // 17*16*64*8 bf16 = 278528 B (A-frag layout, GEMM1)
#define WS_W2   278528     // 8*4*64*8  bf16 = 32768 B  (A-frag layout, GEMM2, *exp(3*logs2))
#define WS_PB   311296     // 64 f32: actnorm_bias[perm[c]]
#define WS_PS   311552     // 64 f32: exp(actnorm_logs[perm[c]])
#define WS_B2S  311808     // 64 f32: b2*exp(3*logs2)

// ---------------------------------------------------------------------------
// Prep: weight repack to bf16 fragment layout + folded per-channel tables +
// logdet init. Runs every launch (graph-capture safe), ~1 MB of L2 traffic.
// ---------------------------------------------------------------------------
__global__ __launch_bounds__(256) void prep_kernel(
    const float* __restrict__ W1, const float* __restrict__ W2,
    const float* __restrict__ anb, const float* __restrict__ anl,
    const int* __restrict__ perm, const float* __restrict__ b2,
    const float* __restrict__ logs2,
    unsigned short* __restrict__ wsW1, unsigned short* __restrict__ wsW2,
    float* __restrict__ pb, float* __restrict__ ps, float* __restrict__ b2s,
    float* __restrict__ out_ld)
{
  int id = blockIdx.x * 256 + threadIdx.x;
  if (id < 544 * 256) {
    // W1T[f][k] = W1[k<512 ? k+32 : k-512][f]  (cond rows first, z1 rows last)
    int feat = id & 255, k = id >> 8;
    int r = (k < 512) ? (k + 32) : (k - 512);
    float v = W1[r * 256 + feat];
    int s = k >> 5, MI = feat >> 4;
    int l = (feat & 15) + 16 * ((k >> 3) & 3), i = k & 7;
    wsW1[((s * 16 + MI) * 64 + l) * 8 + i] = f2bf(v);
  } else if (id < 544 * 256 + 256 * 64) {
    int id2 = id - 544 * 256;
    int ch = id2 & 63, k = id2 >> 6;
    float v = W2[k * 64 + ch] * expf(logs2[ch] * 3.0f);
    int s2 = k >> 5, MI2 = ch >> 4;
    int l = (ch & 15) + 16 * ((k >> 3) & 3), i = k & 7;
    wsW2[((s2 * 4 + MI2) * 64 + l) * 8 + i] = f2bf(v);
  } else {
    int c = id - (544 * 256 + 256 * 64);
    if (c < 64) {
      int p = perm[c];
      pb[c] = anb[p];
      ps[c] = expf(anl[p]);
    } else if (c < 128) {
      int ch = c - 64;
      b2s[ch] = b2[ch] * expf(logs2[ch] * 3.0f);
    } else if (c < 192) {
      int b = c - 128;
      float s = 0.f;
      for (int j = 0; j < 64; ++j) s += anl[j];
      out_ld[b] = (float)T_ * s;   // logdet init, atomics add the rest
    }
  }
}

// ---------------------------------------------------------------------------
// Main fused kernel. 64 tokens/block, 256 threads (4 waves).
// GEMM1 (swapped): H^T(256x64) = W1T(256x544) @ A^T(544x64).
//   Work split 2x2 across waves: wave (wm,wn) computes features wm*128..+127
//   (8 MI frags) x tokens wn*32..+31 (2 NJ frags). B-fragments come DIRECTLY
//   from global cond (each lane: 8 consecutive f32 = 32 contiguous bytes;
//   the 4 lh-groups of a wave cover one full 128 B line per token row).
//   B staging regs are double-buffered (2 chunks in flight, no WAR hazard);
//   A-frags (L2-hot W1) ping-pong one chunk ahead. ZERO barriers in K-loop.
// GEMM2 (swapped): OUT^T(64x64) = W2T(64x256) @ H^T(256x64) via LDS.
// lA (8 KB, z1 tile) and lHT (32 KB) are union-aliased; LDS = 32 KB.
// Epilogue: actnorm+perm gathers, sigmoid/shift/scale, logdet reduce.
// ---------------------------------------------------------------------------
__global__ __launch_bounds__(256) void flow_main(
    const float* __restrict__ input, const float* __restrict__ cond,
    const int* __restrict__ perm, const float* __restrict__ b1,
    const unsigned short* __restrict__ wsW1, const unsigned short* __restrict__ wsW2,
    const float* __restrict__ pb, const float* __restrict__ ps,
    const float* __restrict__ b2s,
    float* __restrict__ out, float* __restrict__ out_ld)
{
  __shared__ union SM {
    short lA[64 * 64];      // [tok][k] bf16 z1 tile, 16B-slot XOR swizzle (8 KB)
    short lHT[64 * 256];    // [tok][feat] bf16, XOR swizzle (32 KB)
  } sm;

  const int tid = threadIdx.x;
  const int w  = tid >> 6;
  const int wm = w >> 1;        // feature half (0..1): features wm*128..+127
  const int wn = w & 1;         // token half   (0..1): tokens   wn*32..+31
  const int l  = tid & 63;
  const int lr = l & 15;
  const int lh = l >> 4;
  const long long m0 = (long long)blockIdx.x * 64;

  // ---- issue B(0), B(1) (HBM cond) as early as possible
  // lane reads tokens (wn*32 + nj*16 + lr), k = q*32 + lh*8 + (0..7)
  const float* cp0 = cond + (m0 + wn * 32 + lr) * 512 + 8 * lh;
  f32x4 bufA0 = *(const f32x4*)(cp0);            // chunk 0, nj=0
  f32x4 bufA1 = *(const f32x4*)(cp0 + 4);
  f32x4 bufA2 = *(const f32x4*)(cp0 + 8192);     // chunk 0, nj=1 (16*512)
  f32x4 bufA3 = *(const f32x4*)(cp0 + 8196);
  f32x4 bufB0 = *(const f32x4*)(cp0 + 32);       // chunk 1, nj=0
  f32x4 bufB1 = *(const f32x4*)(cp0 + 36);
  f32x4 bufB2 = *(const f32x4*)(cp0 + 8224);     // chunk 1, nj=1
  f32x4 bufB3 = *(const f32x4*)(cp0 + 8228);

  // ---- stage z1 (32 permuted+actnormed input channels) into lA
  {
    const int tok = tid >> 2;
    const int c0 = (tid & 3) * 8;
    const float* ip = input + (m0 + tok) * 64;
    short8 v;
#pragma unroll
    for (int j = 0; j < 8; ++j) {
      int c = c0 + j;
      v[j] = (short)f2bf((ip[perm[c]] + pb[c]) * ps[c]);
    }
    const int S = (tid & 3) ^ (tok & 7);
    *(short8*)&sm.lA[tok * 64 + S * 8] = v;
  }

  // ---- A-frag pointers: wave wm covers MI = wm*8 + (0..7)
  // wsW1 index: ((s*16 + MI)*64 + l)*8 ; s-stride = 8192 shorts, MI-stride = 512
  const unsigned short* w1p = wsW1 + ((wm * 8) * 64 + l) * 8;

  short8 aZ[8], aC[8], aN[8];
#pragma unroll
  for (int mi = 0; mi < 8; ++mi)
    aZ[mi] = *(const short8*)&w1p[16 * 8192 + mi * 512];   // z1 K-step (s=16)
#pragma unroll
  for (int mi = 0; mi < 8; ++mi)
    aC[mi] = *(const short8*)&w1p[mi * 512];               // chunk 0 (s=0)

  f32x4 acc[8][2];
#pragma unroll
  for (int mi = 0; mi < 8; ++mi) {
    acc[mi][0] = (f32x4)0.0f;
    acc[mi][1] = (f32x4)0.0f;
  }

  __syncthreads();

  // ---- z1 K-chunk (K=32) from LDS
  {
    short8 bz0, bz1;
    {
      const int tok = wn * 32 + lr;
      const int S = lh ^ (tok & 7);
      bz0 = *(const short8*)&sm.lA[tok * 64 + S * 8];
    }
    {
      const int tok = wn * 32 + 16 + lr;
      const int S = lh ^ (tok & 7);
      bz1 = *(const short8*)&sm.lA[tok * 64 + S * 8];
    }
#pragma unroll
    for (int mi = 0; mi < 8; ++mi) {
      acc[mi][0] = __builtin_amdgcn_mfma_f32_16x16x32_bf16(aZ[mi], bz0, acc[mi][0], 0, 0, 0);
      acc[mi][1] = __builtin_amdgcn_mfma_f32_16x16x32_bf16(aZ[mi], bz1, acc[mi][1], 0, 0, 0);
    }
  }
  __syncthreads();   // all waves done reading lA -> safe to alias as lHT below

  // ---- 16 cond K-chunks (K=32 each), barrier-free, 2-deep B / 1-deep A pipe
#pragma unroll 1
  for (int q = 0; q < 16; q += 2) {
    // even sub-step: consume bufA (chunk q)
    {
      short8 b0 = cvt8(bufA0, bufA1);
      short8 b1f = cvt8(bufA2, bufA3);
      if (q + 2 < 16) {
        const float* cp = cp0 + (q + 2) * 32;
        bufA0 = *(const f32x4*)(cp);
        bufA1 = *(const f32x4*)(cp + 4);
        bufA2 = *(const f32x4*)(cp + 8192);
        bufA3 = *(const f32x4*)(cp + 8196);
      }
#pragma unroll
      for (int mi = 0; mi < 8; ++mi)
        aN[mi] = *(const short8*)&w1p[(q + 1) * 8192 + mi * 512];
#pragma unroll
      for (int mi = 0; mi < 8; ++mi) {
        acc[mi][0] = __builtin_amdgcn_mfma_f32_16x16x32_bf16(aC[mi], b0,  acc[mi][0], 0, 0, 0);
        acc[mi][1] = __builtin_amdgcn_mfma_f32_16x16x32_bf16(aC[mi], b1f, acc[mi][1], 0, 0, 0);
      }
    }
    // odd sub-step: consume bufB (chunk q+1)
    {
      short8 b0 = cvt8(bufB0, bufB1);
      short8 b1f = cvt8(bufB2, bufB3);
      if (q + 3 < 16) {
        const float* cp = cp0 + (q + 3) * 32;
        bufB0 = *(const f32x4*)(cp);
        bufB1 = *(const f32x4*)(cp + 4);
        bufB2 = *(const f32x4*)(cp + 8192);
        bufB3 = *(const f32x4*)(cp + 8196);
      }
      if (q + 2 < 16) {
#pragma unroll
        for (int mi = 0; mi < 8; ++mi)
          aC[mi] = *(const short8*)&w1p[(q + 2) * 8192 + mi * 512];
      }
#pragma unroll
      for (int mi = 0; mi < 8; ++mi) {
        acc[mi][0] = __builtin_amdgcn_mfma_f32_16x16x32_bf16(aN[mi], b0,  acc[mi][0], 0, 0, 0);
        acc[mi][1] = __builtin_amdgcn_mfma_f32_16x16x32_bf16(aN[mi], b1f, acc[mi][1], 0, 0, 0);
      }
    }
  }

  // ---- h = leaky_relu(acc + b1) -> lHT[tok][feat] bf16 (packed b64 writes)
#pragma unroll
  for (int mi = 0; mi < 8; ++mi) {
    const int f0 = wm * 128 + 16 * mi + 4 * lh;
    const f32x4 b1v = *(const f32x4*)&b1[f0];
#pragma unroll
    for (int nj = 0; nj < 2; ++nj) {
      const int tok = wn * 32 + 16 * nj + lr;
      f32x4 v = acc[mi][nj];
      float h0 = v[0] + b1v[0]; h0 = h0 > 0.f ? h0 : 0.01f * h0;
      float h1 = v[1] + b1v[1]; h1 = h1 > 0.f ? h1 : 0.01f * h1;
      float h2 = v[2] + b1v[2]; h2 = h2 > 0.f ? h2 : 0.01f * h2;
      float h3 = v[3] + b1v[3]; h3 = h3 > 0.f ? h3 : 0.01f * h3;
      u32x2 p;
      p[0] = (unsigned)f2bf(h0) | ((unsigned)f2bf(h1) << 16);
      p[1] = (unsigned)f2bf(h2) | ((unsigned)f2bf(h3) << 16);
      const int off = (tok * 512 + f0 * 2) ^ ((tok & 7) << 4);
      *(u32x2*)((char*)sm.lHT + off) = p;
    }
  }

  // prefetch GEMM2 A-frags (L2-hot) — latency hides in the barrier wait
  short8 a2r[8];
#pragma unroll
  for (int s2 = 0; s2 < 8; ++s2)
    a2r[s2] = *(const short8*)&wsW2[((s2 * 4 + w) * 64 + l) * 8];

  __syncthreads();

  // ---- GEMM2: OUT^T = W2T @ H^T
  f32x4 acc2[4];
#pragma unroll
  for (int nj = 0; nj < 4; ++nj) acc2[nj] = (f32x4)0.0f;

#pragma unroll
  for (int s2 = 0; s2 < 8; ++s2) {
#pragma unroll
    for (int nj = 0; nj < 4; ++nj) {
      const int tok = 16 * nj + lr;
      const int off = (tok * 512 + (32 * s2 + 8 * lh) * 2) ^ ((tok & 7) << 4);
      const short8 hb = *(const short8*)((char*)sm.lHT + off);
      acc2[nj] = __builtin_amdgcn_mfma_f32_16x16x32_bf16(a2r[s2], hb, acc2[nj], 0, 0, 0);
    }
  }

  // ---- epilogue: lane holds out-channels {2j0, 2j0+1, 2j0+2, 2j0+3}
  const int j0 = 8 * w + 2 * lh;              // z2-pair indices j0, j0+1
  const int pA = perm[j0],      pB = perm[j0 + 1];
  const int pC = perm[32 + j0], pD = perm[33 + j0];
  const float bA = pb[j0],      sA = ps[j0];
  const float bB = pb[j0 + 1],  sB = ps[j0 + 1];
  const float bC = pb[32 + j0], sC = ps[32 + j0];
  const float bD = pb[33 + j0], sD = ps[33 + j0];
  const f32x4 b2v = *(const f32x4*)&b2s[16 * w + 4 * lh];

  float ldp = 0.f;
#pragma unroll
  for (int nj = 0; nj < 4; ++nj) {
    const long long row = m0 + 16 * nj + lr;
    const float* ip = input + row * 64;
    float* op = out + row * 64;
    f32x4 v = acc2[nj];
    const float sh0 = v[0] + b2v[0];
    const float sc0 = v[1] + b2v[1];
    const float sh1 = v[2] + b2v[2];
    const float sc1 = v[3] + b2v[3];
    const float scl0 = fmaxf(1.f / (1.f + expf(-(sc0 + 2.f))), 1e-6f);
    const float scl1 = fmaxf(1.f / (1.f + expf(-(sc1 + 2.f))), 1e-6f);
    f32x2 z1o, z2o;
    z1o[0] = (ip[pA] + bA) * sA;
    z1o[1] = (ip[pB] + bB) * sB;
    z2o[0] = ((ip[pC] + bC) * sC + sh0) * scl0;
    z2o[1] = ((ip[pD] + bD) * sD + sh1) * scl1;
    *(f32x2*)(op + j0) = z1o;
    *(f32x2*)(op + 32 + j0) = z2o;
    ldp += logf(scl0) + logf(scl1);
  }

#pragma unroll
  for (int off = 32; off > 0; off >>= 1) ldp += __shfl_xor(ldp, off, 64);
  if (l == 0) atomicAdd(&out_ld[blockIdx.x >> 6], ldp);
}

extern "C" void kernel_launch(void* const* d_in, const int* in_sizes, int n_in,
                              void* d_out, int out_size, void* d_ws, size_t ws_size,
                              hipStream_t stream)
{
  const float* input = (const float*)d_in[0];
  const float* cond  = (const float*)d_in[1];
  const float* anb   = (const float*)d_in[2];
  const float* anl   = (const float*)d_in[3];
  const int*   perm  = (const int*)d_in[4];
  const float* W1    = (const float*)d_in[5];
  const float* b1    = (const float*)d_in[6];
  const float* W2    = (const float*)d_in[7];
  const float* b2    = (const float*)d_in[8];
  const float* logs2 = (const float*)d_in[9];

  float* out    = (float*)d_out;
  float* out_ld = out + (long long)B_ * T_ * C_;

  char* ws = (char*)d_ws;
  unsigned short* wsW1 = (unsigned short*)(ws + WS_W1);
  unsigned short* wsW2 = (unsigned short*)(ws + WS_W2);
  float* pbp  = (float*)(ws + WS_PB);
  float* psp  = (float*)(ws + WS_PS);
  float* b2sp = (float*)(ws + WS_B2S);

  prep_kernel<<<609, 256, 0, stream>>>(W1, W2, anb, anl, perm, b2, logs2,
                                       wsW1, wsW2, pbp, psp, b2sp, out_ld);
  flow_main<<<4096, 256, 0, stream>>>(input, cond, perm, b1, wsW1, wsW2,
                                      pbp, psp, b2sp, out, out_ld);
}

// Round 4
// 263.278 us; speedup vs baseline: 3.5832x; 1.2582x over previous
//
#include <hip/hip_runtime.h>
#include <stdint.h>

#define B_ 64
#define T_ 4096
#define C_ 64
#define COND_ 512
#define H_ 256

typedef __attribute__((ext_vector_type(8))) short short8;
typedef __attribute__((ext_vector_type(4))) float f32x4;
typedef __attribute__((ext_vector_type(2))) float f32x2;
typedef __attribute__((ext_vector_type(2))) unsigned int u32x2;

__device__ __forceinline__ unsigned short f2bf(float x) {
  union { float f; unsigned u; } v; v.f = x;
  unsigned r = v.u + 0x7FFFu + ((v.u >> 16) & 1u);
  return (unsigned short)(r >> 16);
}

__device__ __forceinline__ short8 cvt8(f32x4 lo, f32x4 hi) {
  short8 t;
  t[0] = (short)f2bf(lo[0]); t[1] = (short)f2bf(lo[1]);
  t[2] = (short)f2bf(lo[2]); t[3] = (short)f2bf(lo[3]);
  t[4] = (short)f2bf(hi[0]); t[5] = (short)f2bf(hi[1]);
  t[6] = (short)f2bf(hi[2]); t[7] = (short)f2bf(hi[3]);
  return t;
}

// LDS-visibility-only barrier: drains lgkmcnt (ds ops) but leaves global
// loads (vmcnt, VGPR destinations) in flight across the barrier. This is
// what keeps the software pipeline alive — __syncthreads() would emit
// s_waitcnt vmcnt(0) and collapse it.
__device__ __forceinline__ void lgkm_barrier() {
  asm volatile("s_waitcnt lgkmcnt(0)" ::: "memory");
  __builtin_amdgcn_s_barrier();
}

// ws layout (bytes)
#define WS_W1   0          // 17*16*64*8 bf16 = 278528 B (A-frag layout, GEMM1)
#define WS_W2   278528     // 8*4*64*8  bf16 = 32768 B  (A-frag layout, GEMM2, *exp(3*logs2))
#define WS_PB   311296     // 64 f32: actnorm_bias[perm[c]]
#define WS_PS   311552     // 64 f32: exp(actnorm_logs[perm[c]])
#define WS_B2S  311808     // 64 f32: b2*exp(3*logs2)

// ---------------------------------------------------------------------------
// Prep: weight repack to bf16 fragment layout + folded per-channel tables +
// logdet init. Runs every launch (graph-capture safe), ~1 MB of L2 traffic.
// ---------------------------------------------------------------------------
__global__ __launch_bounds__(256) void prep_kernel(
    const float* __restrict__ W1, const float* __restrict__ W2,
    const float* __restrict__ anb, const float* __restrict__ anl,
    const int* __restrict__ perm, const float* __restrict__ b2,
    const float* __restrict__ logs2,
    unsigned short* __restrict__ wsW1, unsigned short* __restrict__ wsW2,
    float* __restrict__ pb, float* __restrict__ ps, float* __restrict__ b2s,
    float* __restrict__ out_ld)
{
  int id = blockIdx.x * 256 + threadIdx.x;
  if (id < 544 * 256) {
    // W1T[f][k] = W1[k<512 ? k+32 : k-512][f]  (cond rows first, z1 rows last)
    int feat = id & 255, k = id >> 8;
    int r = (k < 512) ? (k + 32) : (k - 512);
    float v = W1[r * 256 + feat];
    int s = k >> 5, MI = feat >> 4;
    int l = (feat & 15) + 16 * ((k >> 3) & 3), i = k & 7;
    wsW1[((s * 16 + MI) * 64 + l) * 8 + i] = f2bf(v);
  } else if (id < 544 * 256 + 256 * 64) {
    int id2 = id - 544 * 256;
    int ch = id2 & 63, k = id2 >> 6;
    float v = W2[k * 64 + ch] * expf(logs2[ch] * 3.0f);
    int s2 = k >> 5, MI2 = ch >> 4;
    int l = (ch & 15) + 16 * ((k >> 3) & 3), i = k & 7;
    wsW2[((s2 * 4 + MI2) * 64 + l) * 8 + i] = f2bf(v);
  } else {
    int c = id - (544 * 256 + 256 * 64);
    if (c < 64) {
      int p = perm[c];
      pb[c] = anb[p];
      ps[c] = expf(anl[p]);
    } else if (c < 128) {
      int ch = c - 64;
      b2s[ch] = b2[ch] * expf(logs2[ch] * 3.0f);
    } else if (c < 192) {
      int b = c - 128;
      float s = 0.f;
      for (int j = 0; j < 64; ++j) s += anl[j];
      out_ld[b] = (float)T_ * s;   // logdet init, atomics add the rest
    }
  }
}

// ---------------------------------------------------------------------------
// Main fused kernel. 64 tokens/block, 256 threads (4 waves).
// GEMM1 (swapped): H^T(256x64) = W1T(256x544) @ A^T(544x64).
//   Round-0 LDS-staged structure, rescheduled as a true 2-stage pipeline:
//   chunk c's W1 A-frags (afX) AND cond staging regs (sX) are both issued
//   during iteration c-1, ordered [af, st] within the group so that the
//   in-order vmcnt wait for af(c) at MFMA(c+1) does NOT drain st(c), and
//   the wait for st(c) at the write phase does not drain group c+1.
//   Barriers are lgkmcnt-only (raw s_barrier) so global loads fly across.
// GEMM2 (swapped): OUT^T(64x64) = W2T(64x256) @ H^T(256x64).
// lA (16 KB, GEMM1 staging) and lHT (32 KB, GEMM2 input) have disjoint
// lifetimes -> union alias, LDS 32 KB.
// Epilogue: actnorm+perm gathers, sigmoid/shift/scale, logdet reduce.
// ---------------------------------------------------------------------------
__global__ __launch_bounds__(256) void flow_main(
    const float* __restrict__ input, const float* __restrict__ cond,
    const int* __restrict__ perm, const float* __restrict__ b1,
    const unsigned short* __restrict__ wsW1, const unsigned short* __restrict__ wsW2,
    const float* __restrict__ pb, const float* __restrict__ ps,
    const float* __restrict__ b2s,
    float* __restrict__ out, float* __restrict__ out_ld)
{
  __shared__ union SM {
    short lA[2][64 * 64];   // [buf][tok][k] bf16, 16B-slot XOR swizzle (GEMM1)
    short lHT[64 * 256];    // [tok][feat] bf16, XOR swizzle (GEMM2)
  } sm;

  const int tid = threadIdx.x;
  const int w  = tid >> 6;
  const int l  = tid & 63;
  const int lr = l & 15;
  const int lh = l >> 4;
  const long long m0 = (long long)blockIdx.x * 64;

  const int stok = tid >> 2;
  const int skc  = (tid & 3) * 16;
  const float* cpS = cond + (m0 + stok) * 512 + skc;   // + chunk*64

#define W1F(s, mi) (*(const short8*)&wsW1[((((s) * 16) + (4 * w + (mi))) * 64 + l) * 8])

  // ---- prologue prefetch: z1 A-frags (oldest), then [afA,stA]=chunk0,
  // [afB,stB]=chunk1. Group order matters for in-order vmcnt semantics.
  short8 aZ[4];
#pragma unroll
  for (int mi = 0; mi < 4; ++mi) aZ[mi] = W1F(16, mi);

  short8 afA[2][4], afB[2][4];
#pragma unroll
  for (int h = 0; h < 2; ++h)
#pragma unroll
    for (int mi = 0; mi < 4; ++mi) afA[h][mi] = W1F(h, mi);
  f32x4 sA0 = *(const f32x4*)(cpS);
  f32x4 sA1 = *(const f32x4*)(cpS + 4);
  f32x4 sA2 = *(const f32x4*)(cpS + 8);
  f32x4 sA3 = *(const f32x4*)(cpS + 12);

#pragma unroll
  for (int h = 0; h < 2; ++h)
#pragma unroll
    for (int mi = 0; mi < 4; ++mi) afB[h][mi] = W1F(2 + h, mi);
  f32x4 sB0 = *(const f32x4*)(cpS + 64);
  f32x4 sB1 = *(const f32x4*)(cpS + 68);
  f32x4 sB2 = *(const f32x4*)(cpS + 72);
  f32x4 sB3 = *(const f32x4*)(cpS + 76);

  // ---- stage z1 (32 permuted+actnormed input channels) into lA[0]
  {
    const int c0 = (tid & 3) * 8;
    const float* ip = input + (m0 + stok) * 64;
    short8 v;
#pragma unroll
    for (int j = 0; j < 8; ++j) {
      int c = c0 + j;
      v[j] = (short)f2bf((ip[perm[c]] + pb[c]) * ps[c]);
    }
    const int S = (tid & 3) ^ (stok & 7);
    *(short8*)&sm.lA[0][stok * 64 + S * 8] = v;
  }

  f32x4 acc[4][4];
#pragma unroll
  for (int mi = 0; mi < 4; ++mi)
#pragma unroll
    for (int nj = 0; nj < 4; ++nj)
      acc[mi][nj] = (f32x4)0.0f;

  lgkm_barrier();

  // ---- iter 0: MFMA z1 (1 K-step) from lA[0]; write chunk0 (stA) -> lA[1]
  {
    short8 bz[4];
#pragma unroll
    for (int nj = 0; nj < 4; ++nj) {
      const int tok = 16 * nj + lr;
      bz[nj] = *(const short8*)&sm.lA[0][tok * 64 + ((lh ^ (tok & 7)) * 8)];
    }
#pragma unroll
    for (int mi = 0; mi < 4; ++mi)
#pragma unroll
      for (int nj = 0; nj < 4; ++nj)
        acc[mi][nj] = __builtin_amdgcn_mfma_f32_16x16x32_bf16(
            aZ[mi], bz[nj], acc[mi][nj], 0, 0, 0);

    short8 c0v = cvt8(sA0, sA1), c1v = cvt8(sA2, sA3);
    const int S0 = 2 * (tid & 3);
    *(short8*)&sm.lA[1][stok * 64 + ((S0 ^ (stok & 7)) * 8)] = c0v;
    *(short8*)&sm.lA[1][stok * 64 + (((S0 + 1) ^ (stok & 7)) * 8)] = c1v;
  }
  lgkm_barrier();

  // ---- pipelined main loop: p covers iters (2p+1, 2p+2), chunks 0..7
#pragma unroll 1
  for (int p = 0; p < 4; ++p) {
    // ===== odd iter (it=2p+1): MFMA chunk 2p (afA) from lA[1]
    {
      short8 bf0[4], bf1[4];
#pragma unroll
      for (int nj = 0; nj < 4; ++nj) {
        const int tok = 16 * nj + lr;
        bf0[nj] = *(const short8*)&sm.lA[1][tok * 64 + ((lh ^ (tok & 7)) * 8)];
        bf1[nj] = *(const short8*)&sm.lA[1][tok * 64 + (((4 + lh) ^ (tok & 7)) * 8)];
      }
#pragma unroll
      for (int mi = 0; mi < 4; ++mi)
#pragma unroll
        for (int nj = 0; nj < 4; ++nj)
          acc[mi][nj] = __builtin_amdgcn_mfma_f32_16x16x32_bf16(
              afA[0][mi], bf0[nj], acc[mi][nj], 0, 0, 0);
#pragma unroll
      for (int mi = 0; mi < 4; ++mi)
#pragma unroll
        for (int nj = 0; nj < 4; ++nj)
          acc[mi][nj] = __builtin_amdgcn_mfma_f32_16x16x32_bf16(
              afA[1][mi], bf1[nj], acc[mi][nj], 0, 0, 0);
    }
    // issue chunk 2p+2 group [afA, stA]
    if (p <= 2) {
#pragma unroll
      for (int h = 0; h < 2; ++h)
#pragma unroll
        for (int mi = 0; mi < 4; ++mi) afA[h][mi] = W1F(4 * p + 4 + h, mi);
      const float* cp = cpS + (2 * p + 2) * 64;
      sA0 = *(const f32x4*)(cp);
      sA1 = *(const f32x4*)(cp + 4);
      sA2 = *(const f32x4*)(cp + 8);
      sA3 = *(const f32x4*)(cp + 12);
    }
    // write chunk 2p+1 (stB) -> lA[0]
    {
      short8 c0v = cvt8(sB0, sB1), c1v = cvt8(sB2, sB3);
      const int S0 = 2 * (tid & 3);
      *(short8*)&sm.lA[0][stok * 64 + ((S0 ^ (stok & 7)) * 8)] = c0v;
      *(short8*)&sm.lA[0][stok * 64 + (((S0 + 1) ^ (stok & 7)) * 8)] = c1v;
    }
    lgkm_barrier();

    // ===== even iter (it=2p+2): MFMA chunk 2p+1 (afB) from lA[0]
    {
      short8 bf0[4], bf1[4];
#pragma unroll
      for (int nj = 0; nj < 4; ++nj) {
        const int tok = 16 * nj + lr;
        bf0[nj] = *(const short8*)&sm.lA[0][tok * 64 + ((lh ^ (tok & 7)) * 8)];
        bf1[nj] = *(const short8*)&sm.lA[0][tok * 64 + (((4 + lh) ^ (tok & 7)) * 8)];
      }
#pragma unroll
      for (int mi = 0; mi < 4; ++mi)
#pragma unroll
        for (int nj = 0; nj < 4; ++nj)
          acc[mi][nj] = __builtin_amdgcn_mfma_f32_16x16x32_bf16(
              afB[0][mi], bf0[nj], acc[mi][nj], 0, 0, 0);
#pragma unroll
      for (int mi = 0; mi < 4; ++mi)
#pragma unroll
        for (int nj = 0; nj < 4; ++nj)
          acc[mi][nj] = __builtin_amdgcn_mfma_f32_16x16x32_bf16(
              afB[1][mi], bf1[nj], acc[mi][nj], 0, 0, 0);
    }
    // issue chunk 2p+3 group [afB, stB]
    if (p <= 2) {
#pragma unroll
      for (int h = 0; h < 2; ++h)
#pragma unroll
        for (int mi = 0; mi < 4; ++mi) afB[h][mi] = W1F(4 * p + 6 + h, mi);
      const float* cp = cpS + (2 * p + 3) * 64;
      sB0 = *(const f32x4*)(cp);
      sB1 = *(const f32x4*)(cp + 4);
      sB2 = *(const f32x4*)(cp + 8);
      sB3 = *(const f32x4*)(cp + 12);
    }
    // write chunk 2p+2 (stA) -> lA[1]
    if (p <= 2) {
      short8 c0v = cvt8(sA0, sA1), c1v = cvt8(sA2, sA3);
      const int S0 = 2 * (tid & 3);
      *(short8*)&sm.lA[1][stok * 64 + ((S0 ^ (stok & 7)) * 8)] = c0v;
      *(short8*)&sm.lA[1][stok * 64 + (((S0 + 1) ^ (stok & 7)) * 8)] = c1v;
    }
    lgkm_barrier();
  }

  // ---- h = leaky_relu(acc + b1) -> lHT[tok][feat] bf16 (packed b64 writes)
  // lA is dead from here (barrier above) — lHT aliases it.
#pragma unroll
  for (int mi = 0; mi < 4; ++mi) {
    const int f0 = 64 * w + 16 * mi + 4 * lh;
    const f32x4 b1v = *(const f32x4*)&b1[f0];
#pragma unroll
    for (int nj = 0; nj < 4; ++nj) {
      const int tok = 16 * nj + lr;
      f32x4 v = acc[mi][nj];
      float h0 = v[0] + b1v[0]; h0 = h0 > 0.f ? h0 : 0.01f * h0;
      float h1 = v[1] + b1v[1]; h1 = h1 > 0.f ? h1 : 0.01f * h1;
      float h2 = v[2] + b1v[2]; h2 = h2 > 0.f ? h2 : 0.01f * h2;
      float h3 = v[3] + b1v[3]; h3 = h3 > 0.f ? h3 : 0.01f * h3;
      u32x2 pk;
      pk[0] = (unsigned)f2bf(h0) | ((unsigned)f2bf(h1) << 16);
      pk[1] = (unsigned)f2bf(h2) | ((unsigned)f2bf(h3) << 16);
      const int off = (tok * 512 + f0 * 2) ^ ((tok & 7) << 4);
      *(u32x2*)((char*)sm.lHT + off) = pk;
    }
  }

  // prefetch GEMM2 A-frags (L2-hot) — latency hides in the barrier wait
  short8 a2r[8];
#pragma unroll
  for (int s2 = 0; s2 < 8; ++s2)
    a2r[s2] = *(const short8*)&wsW2[((s2 * 4 + w) * 64 + l) * 8];

  lgkm_barrier();

  // ---- GEMM2: OUT^T = W2T @ H^T
  f32x4 acc2[4];
#pragma unroll
  for (int nj = 0; nj < 4; ++nj) acc2[nj] = (f32x4)0.0f;

#pragma unroll
  for (int s2 = 0; s2 < 8; ++s2) {
#pragma unroll
    for (int nj = 0; nj < 4; ++nj) {
      const int tok = 16 * nj + lr;
      const int off = (tok * 512 + (32 * s2 + 8 * lh) * 2) ^ ((tok & 7) << 4);
      const short8 hb = *(const short8*)((char*)sm.lHT + off);
      acc2[nj] = __builtin_amdgcn_mfma_f32_16x16x32_bf16(a2r[s2], hb, acc2[nj], 0, 0, 0);
    }
  }

  // ---- epilogue: lane holds out-channels {2j0, 2j0+1, 2j0+2, 2j0+3}
  const int j0 = 8 * w + 2 * lh;              // z2-pair indices j0, j0+1
  const int pA = perm[j0],      pB = perm[j0 + 1];
  const int pC = perm[32 + j0], pD = perm[33 + j0];
  const float bA = pb[j0],      sA = ps[j0];
  const float bB = pb[j0 + 1],  sB = ps[j0 + 1];
  const float bC = pb[32 + j0], sC = ps[32 + j0];
  const float bD = pb[33 + j0], sD = ps[33 + j0];
  const f32x4 b2v = *(const f32x4*)&b2s[16 * w + 4 * lh];

  float ldp = 0.f;
#pragma unroll
  for (int nj = 0; nj < 4; ++nj) {
    const long long row = m0 + 16 * nj + lr;
    const float* ip = input + row * 64;
    float* op = out + row * 64;
    f32x4 v = acc2[nj];
    const float sh0 = v[0] + b2v[0];
    const float sc0 = v[1] + b2v[1];
    const float sh1 = v[2] + b2v[2];
    const float sc1 = v[3] + b2v[3];
    const float scl0 = fmaxf(1.f / (1.f + expf(-(sc0 + 2.f))), 1e-6f);
    const float scl1 = fmaxf(1.f / (1.f + expf(-(sc1 + 2.f))), 1e-6f);
    f32x2 z1o, z2o;
    z1o[0] = (ip[pA] + bA) * sA;
    z1o[1] = (ip[pB] + bB) * sB;
    z2o[0] = ((ip[pC] + bC) * sC + sh0) * scl0;
    z2o[1] = ((ip[pD] + bD) * sD + sh1) * scl1;
    *(f32x2*)(op + j0) = z1o;
    *(f32x2*)(op + 32 + j0) = z2o;
    ldp += logf(scl0) + logf(scl1);
  }

#pragma unroll
  for (int off = 32; off > 0; off >>= 1) ldp += __shfl_xor(ldp, off, 64);
  if (l == 0) atomicAdd(&out_ld[blockIdx.x >> 6], ldp);
}

extern "C" void kernel_launch(void* const* d_in, const int* in_sizes, int n_in,
                              void* d_out, int out_size, void* d_ws, size_t ws_size,
                              hipStream_t stream)
{
  const float* input = (const float*)d_in[0];
  const float* cond  = (const float*)d_in[1];
  const float* anb   = (const float*)d_in[2];
  const float* anl   = (const float*)d_in[3];
  const int*   perm  = (const int*)d_in[4];
  const float* W1    = (const float*)d_in[5];
  const float* b1    = (const float*)d_in[6];
  const float* W2    = (const float*)d_in[7];
  const float* b2    = (const float*)d_in[8];
  const float* logs2 = (const float*)d_in[9];

  float* out    = (float*)d_out;
  float* out_ld = out + (long long)B_ * T_ * C_;

  char* ws = (char*)d_ws;
  unsigned short* wsW1 = (unsigned short*)(ws + WS_W1);
  unsigned short* wsW2 = (unsigned short*)(ws + WS_W2);
  float* pbp  = (float*)(ws + WS_PB);
  float* psp  = (float*)(ws + WS_PS);
  float* b2sp = (float*)(ws + WS_B2S);

  prep_kernel<<<609, 256, 0, stream>>>(W1, W2, anb, anl, perm, b2, logs2,
                                       wsW1, wsW2, pbp, psp, b2sp, out_ld);
  flow_main<<<4096, 256, 0, stream>>>(input, cond, perm, b1, wsW1, wsW2,
                                      pbp, psp, b2sp, out, out_ld);
}